// Round 8
// baseline (632.913 us; speedup 1.0000x reference)
//
#include <hip/hip_runtime.h>
#include <stdint.h>

// VQ-VAE nearest-codebook index: N=32768 queries, D=64, K=8192 codes.
// R8 = R6-proven 5-kernel skeleton with:
//  - vq_mfma at launch_bounds(256,3) (cap 170 VGPR; no spill) + split-K=8
//    (grid 2048) -> 3 blocks/CU, finer tail. R7 fused-barrier approach reverted
//    (grid<=512 co-residency halved waves/CU -> 2.4x slower phase 1).
//  - vq_exact3: k-tiled exact phase, codebook staged once per block in LDS
//    (padded CBP=129 -> conflict-free), 16 MB total traffic vs cnt*2MB.
// Phase A math identical to validated R6 (bf16x3 split, s2 certification).

#define N_TOTAL 32768
#define K_CODES 8192
#define EPS_GAP 0.015f
#define NPART   8

typedef __attribute__((ext_vector_type(16))) float  floatx16;
typedef __attribute__((ext_vector_type(8)))  __bf16 bf16x8;

// ---- workspace layout (bytes) ----
#define O_C2    0u          // 8192 f32
#define O_CBSW  32768u      // [256 kBlk][16 cg][32 m][8 bf16] = 2 MB
#define O_PS1   2129920u    // 8*32768 f32
#define O_PS2   3178496u    // 8*32768 f32
#define O_PI1   4227072u    // 8*32768 i32
#define O_CNT   5275648u
#define O_LIST  5275904u    // 32768 int
#define O_SLOT  5406976u    // 32768 u64
#define WS_NEED 5669120u    // (R3 proved ws >= 11.7 MB)

#if defined(__has_builtin)
#if __has_builtin(__builtin_amdgcn_fmed3f)
#define MED3(a, b, c) __builtin_amdgcn_fmed3f((a), (b), (c))
#endif
#endif
#ifndef MED3
#define MED3(a, b, c) fminf((c), fmaxf((a), (b)))
#endif

__device__ __forceinline__ unsigned int fkey(float s) {
    unsigned int u = __float_as_uint(s);
    return (u & 0x80000000u) ? ~u : (u | 0x80000000u);
}

__device__ __forceinline__ void load_lds16(const void* g, void* l) {
    __builtin_amdgcn_global_load_lds(
        (const __attribute__((address_space(1))) unsigned int*)g,
        (__attribute__((address_space(3))) unsigned int*)l, 16, 0, 0);
}

// ---- prep: split codebook into hi/lo bf16 fragments + row norms + cnt=0 ----
__global__ __launch_bounds__(256) void vq_prep(
    const float4* __restrict__ cb, uint4* __restrict__ cbSw,
    float* __restrict__ c2, int* __restrict__ cnt) {
    __shared__ float red[256];
    const int m = threadIdx.x & 31, g = threadIdx.x >> 5;
    const int rb = blockIdx.x;
    if (rb == 0 && threadIdx.x == 0) *cnt = 0;
    float4 a = cb[(size_t)(rb * 32 + m) * 16 + g * 2];
    float4 b = cb[(size_t)(rb * 32 + m) * 16 + g * 2 + 1];
    float x[8] = {a.x, a.y, a.z, a.w, b.x, b.y, b.z, b.w};
    bf16x8 hv, lv;
    float ss = 0.f;
#pragma unroll
    for (int i = 0; i < 8; ++i) {
        float v  = x[i];
        __bf16 hb = (__bf16)v;           // RNE
        float r  = v - (float)hb;
        hv[i] = hb;
        lv[i] = (__bf16)r;
        ss += v * v;
    }
    cbSw[(size_t)rb * 512 + g * 32 + m]       = __builtin_bit_cast(uint4, hv);
    cbSw[(size_t)rb * 512 + (8 + g) * 32 + m] = __builtin_bit_cast(uint4, lv);
    red[threadIdx.x] = ss;
    __syncthreads();
    if (threadIdx.x < 32) {
        float s = 0.f;
#pragma unroll
        for (int gg = 0; gg < 8; ++gg) s += red[threadIdx.x + 32 * gg];
        c2[rb * 32 + threadIdx.x] = s;
    }
}

// ---- phase A: 128 queries x 1024 codes per block (split-K=8) ----
__global__ __launch_bounds__(256, 3) void vq_mfma(
    const float4* __restrict__ lat, const uint4* __restrict__ cbSw,
    const float* __restrict__ c2,
    float* __restrict__ pS1, float* __restrict__ pS2, int* __restrict__ pI1) {
    __shared__ uint4 Bs[2048];   // 32 KB: [4 kb][16 cg][32 m]
    const int tid = threadIdx.x;
    const int wr = tid >> 6, lane = tid & 63;
    const int m = lane & 31, h = lane >> 5;

    // A fragments: split in-kernel from raw fp32 (identical math to vq_prep).
    const int q = blockIdx.x * 128 + wr * 32 + m;
    bf16x8 aH[4], aL[4];
#pragma unroll
    for (int c = 0; c < 4; ++c) {
        float4 v0 = lat[(size_t)q * 16 + c * 4 + h * 2];
        float4 v1 = lat[(size_t)q * 16 + c * 4 + h * 2 + 1];
        float x[8] = {v0.x, v0.y, v0.z, v0.w, v1.x, v1.y, v1.z, v1.w};
#pragma unroll
        for (int j = 0; j < 8; ++j) {
            float v  = x[j];
            __bf16 hb = (__bf16)v;
            aH[c][j] = hb;
            aL[c][j] = (__bf16)(v - (float)hb);
        }
    }

    float s1[16], s2[16]; int i1[16];
#pragma unroll
    for (int r = 0; r < 16; ++r) { s1[r] = 3e38f; s2[r] = 3e38f; i1[r] = 0; }

    const int kBase = blockIdx.y * 1024;

    for (int stage = 0; stage < 8; ++stage) {
        const int rbBase = blockIdx.y * 32 + stage * 4;
        __syncthreads();
#pragma unroll
        for (int i = 0; i < 8; ++i)
            load_lds16(&cbSw[(size_t)rbBase * 512 + wr * 64 + 256 * i + lane],
                       &Bs[wr * 64 + 256 * i]);
        __syncthreads();

#pragma unroll
        for (int kb = 0; kb < 4; ++kb) {
            const int col = kBase + stage * 128 + kb * 32 + m;
            const float cc = c2[col];
            floatx16 acc;
#pragma unroll
            for (int r = 0; r < 16; ++r) acc[r] = 0.f;
#pragma unroll
            for (int c = 0; c < 4; ++c) {
                bf16x8 bH = __builtin_bit_cast(bf16x8, Bs[kb * 512 + (c * 2 + h) * 32 + m]);
                bf16x8 bL = __builtin_bit_cast(bf16x8, Bs[kb * 512 + (8 + c * 2 + h) * 32 + m]);
                acc = __builtin_amdgcn_mfma_f32_32x32x16_bf16(aH[c], bH, acc, 0, 0, 0);
                acc = __builtin_amdgcn_mfma_f32_32x32x16_bf16(aL[c], bH, acc, 0, 0, 0);
                acc = __builtin_amdgcn_mfma_f32_32x32x16_bf16(aH[c], bL, acc, 0, 0, 0);
            }
#pragma unroll
            for (int r = 0; r < 16; ++r) {
                float s = fmaf(-2.f, acc[r], cc);
                s2[r] = MED3(s, s1[r], s2[r]);       // = min(s2, max(s, s1))
                bool lt = s < s1[r];
                i1[r] = lt ? col : i1[r];
                s1[r] = lt ? s : s1[r];
            }
        }
    }

    // reduce (s1,i1,s2) across the 32 column-lanes of each half
#pragma unroll
    for (int mask = 1; mask <= 16; mask <<= 1) {
#pragma unroll
        for (int r = 0; r < 16; ++r) {
            float o1 = __shfl_xor(s1[r], mask);
            float o2 = __shfl_xor(s2[r], mask);
            int   oi = __shfl_xor(i1[r], mask);
            float n2 = fminf(fminf(s2[r], o2), fmaxf(s1[r], o1));
            bool take = (o1 < s1[r]) || (o1 == s1[r] && oi < i1[r]);
            s1[r] = take ? o1 : s1[r];
            i1[r] = take ? oi : i1[r];
            s2[r] = n2;
        }
    }

    if (m == 0) {
        const int qb = blockIdx.x * 128 + wr * 32;
        const int o0 = blockIdx.y * N_TOTAL;
#pragma unroll
        for (int r = 0; r < 16; ++r) {
            int row = (r & 3) + 8 * (r >> 2) + 4 * h;   // C/D layout row
            int qq = qb + row;
            pS1[o0 + qq] = s1[r];
            pS2[o0 + qq] = s2[r];
            pI1[o0 + qq] = i1[r];
        }
    }
}

// ---- merge 8 split-K partitions, write indices, flag near-ties ----
__global__ void vq_merge8(const float* __restrict__ pS1, const float* __restrict__ pS2,
                          const int* __restrict__ pI1, int* __restrict__ out,
                          int* __restrict__ cnt, int* __restrict__ list,
                          unsigned long long* __restrict__ slot) {
    int q = blockIdx.x * 256 + threadIdx.x;
    float g1 = 3e38f, g2 = 3e38f;
    int   gi = 0x7FFFFFFF;
#pragma unroll
    for (int p = 0; p < NPART; ++p) {
        float s1p = pS1[p * N_TOTAL + q];
        float s2p = pS2[p * N_TOTAL + q];
        int   i1p = pI1[p * N_TOTAL + q];
        bool take = (s1p < g1) || (s1p == g1 && i1p < gi);
        g2 = fminf(g2, fminf(s2p, take ? g1 : s1p));
        if (take) { g1 = s1p; gi = i1p; }
    }
    out[q] = gi;
    if (g2 - g1 < EPS_GAP) {
        int e = atomicAdd(cnt, 1);
        list[e] = q;
        slot[e] = 0xFFFFFFFFFFFFFFFFull;
    }
}

// ---- phase B: exact fp32, k-tiled shared-codebook scan ----
// grid (64,8): blockIdx.x = 128-code slice, blockIdx.y = flagged-query group.
// Codebook staged once per block in LDS, padded (CBP=129): writes hit 8 banks
// 2-way (free), reads broadcast per lane pair (free).
#define CBP 129
__global__ __launch_bounds__(256) void vq_exact3(
    const float4* __restrict__ lat, const float4* __restrict__ cb,
    const float* __restrict__ c2, const int* __restrict__ cnt,
    const int* __restrict__ list, unsigned long long* __restrict__ slot) {
    __shared__ float CbT[64 * CBP];   // 33024 B
    __shared__ float c2s[128];
    const int n = *cnt;
    if (n == 0) return;
    const int ks = blockIdx.x;
    const int egrp = blockIdx.y;
    const int tid = threadIdx.x;
    for (int i = tid; i < 2048; i += 256) {
        int code = i >> 4, d4 = i & 15;
        float4 v = cb[(size_t)(ks * 128 + code) * 16 + d4];
        CbT[(d4 * 4 + 0) * CBP + code] = v.x;
        CbT[(d4 * 4 + 1) * CBP + code] = v.y;
        CbT[(d4 * 4 + 2) * CBP + code] = v.z;
        CbT[(d4 * 4 + 3) * CBP + code] = v.w;
    }
    if (tid < 128) c2s[tid] = c2[ks * 128 + tid];
    __syncthreads();

    const int code = tid >> 1, dh = tid & 1;   // 2 lanes per code: D-halves
    for (int e = egrp; e < n; e += 8) {
        const int qq = list[e];
        const float4* qp = lat + (size_t)qq * 16 + dh * 8;
        float dot = 0.f;
#pragma unroll
        for (int j = 0; j < 8; ++j) {
            float4 qv = qp[j];
            dot += qv.x * CbT[(dh * 32 + j * 4 + 0) * CBP + code]
                 + qv.y * CbT[(dh * 32 + j * 4 + 1) * CBP + code]
                 + qv.z * CbT[(dh * 32 + j * 4 + 2) * CBP + code]
                 + qv.w * CbT[(dh * 32 + j * 4 + 3) * CBP + code];
        }
        dot += __shfl_xor(dot, 1);             // combine the two D-halves
        float s = c2s[code] - 2.f * dot;
        unsigned long long p =
            ((unsigned long long)fkey(s) << 32) | (unsigned)(ks * 128 + code);
#pragma unroll
        for (int mask = 1; mask <= 32; mask <<= 1) {
            unsigned long long o = __shfl_xor(p, mask);
            p = o < p ? o : p;
        }
        if ((tid & 63) == 0) atomicMin(&slot[e], p);
    }
}

// ---- write back exact answers for flagged queries ----
__global__ void vq_write(const int* __restrict__ cnt, const int* __restrict__ list,
                         const unsigned long long* __restrict__ slot,
                         int* __restrict__ out) {
    int t = blockIdx.x * 256 + threadIdx.x;
    if (t < *cnt) out[list[t]] = (int)(slot[t] & 0xFFFFFFFFull);
}

// ================= fallback: validated round-1 fp32 path =================
#define BM 128
#define BN 128
#define PAD 68

__global__ void vq_norms_fb(const float4* __restrict__ cb, float* __restrict__ c2) {
    int t = blockIdx.x * 256 + threadIdx.x;
    int r = t >> 2, p = t & 3;
    float s = 0.f;
#pragma unroll
    for (int i = 0; i < 4; ++i) {
        float4 v = cb[r * 16 + p * 4 + i];
        s += v.x * v.x + v.y * v.y + v.z * v.z + v.w * v.w;
    }
    s += __shfl_xor(s, 1);
    s += __shfl_xor(s, 2);
    if (p == 0) c2[r] = s;
}

__global__ __launch_bounds__(256) void vq_fp32(
    const float4* __restrict__ lat, const float4* __restrict__ cb,
    const float* __restrict__ c2, int ktPer,
    int* __restrict__ outIdx, float* __restrict__ partS, int* __restrict__ partI,
    int writePartial) {
    __shared__ float As[BM][PAD];
    __shared__ float Bsf[BN][PAD];
    __shared__ float c2s[BN];
    const int tid = threadIdx.x;
    const int tx = tid & 15;
    const int ty = tid >> 4;
    const int nBase = blockIdx.x * BM;
    const int kt0 = blockIdx.y * ktPer;
    const int ktN = kt0 + ktPer;
#pragma unroll
    for (int r = 0; r < 8; ++r) {
        int f = tid + 256 * r;
        int mm = f >> 4, d4 = f & 15;
        float4 v = lat[(size_t)(nBase + mm) * 16 + d4];
        *(float4*)&As[mm][d4 * 4] = v;
    }
    float best[8]; int bidx[8];
#pragma unroll
    for (int ii = 0; ii < 8; ++ii) { best[ii] = 3e38f; bidx[ii] = 0; }
    for (int kt = kt0; kt < ktN; ++kt) {
        const int kbase = kt * BN;
        __syncthreads();
#pragma unroll
        for (int r = 0; r < 8; ++r) {
            int f = tid + 256 * r;
            int k = f >> 4, d4 = f & 15;
            float4 v = cb[(size_t)(kbase + k) * 16 + d4];
            *(float4*)&Bsf[k][d4 * 4] = v;
        }
        if (tid < BN) c2s[tid] = c2[kbase + tid];
        __syncthreads();
        float acc[8][8];
#pragma unroll
        for (int ii = 0; ii < 8; ++ii)
#pragma unroll
            for (int jj = 0; jj < 8; ++jj) acc[ii][jj] = 0.f;
#pragma unroll 4
        for (int d4 = 0; d4 < 16; ++d4) {
            float4 a[8], b[8];
#pragma unroll
            for (int ii = 0; ii < 8; ++ii) a[ii] = *(const float4*)&As[tx + 16 * ii][d4 * 4];
#pragma unroll
            for (int jj = 0; jj < 8; ++jj) b[jj] = *(const float4*)&Bsf[ty + 16 * jj][d4 * 4];
#pragma unroll
            for (int ii = 0; ii < 8; ++ii)
#pragma unroll
                for (int jj = 0; jj < 8; ++jj)
                    acc[ii][jj] += a[ii].x * b[jj].x + a[ii].y * b[jj].y
                                 + a[ii].z * b[jj].z + a[ii].w * b[jj].w;
        }
#pragma unroll
        for (int jj = 0; jj < 8; ++jj) {
            int k = kbase + ty + 16 * jj;
            float cc = c2s[ty + 16 * jj];
#pragma unroll
            for (int ii = 0; ii < 8; ++ii) {
                float s = cc - 2.f * acc[ii][jj];
                if (s < best[ii]) { best[ii] = s; bidx[ii] = k; }
            }
        }
    }
    __syncthreads();
    float* redS = &As[0][0];
    int*   redI = (int*)&Bsf[0][0];
#pragma unroll
    for (int ii = 0; ii < 8; ++ii) {
        int mm = tx + 16 * ii;
        redS[ty * BM + mm] = best[ii];
        redI[ty * BM + mm] = bidx[ii];
    }
    __syncthreads();
    if (tid < BM) {
        int mm = tid;
        float bs = redS[mm]; int bi = redI[mm];
#pragma unroll
        for (int t = 1; t < 16; ++t) {
            float s = redS[t * BM + mm]; int i = redI[t * BM + mm];
            if (s < bs || (s == bs && i < bi)) { bs = s; bi = i; }
        }
        int n = nBase + mm;
        if (writePartial) { partS[blockIdx.y * N_TOTAL + n] = bs; partI[blockIdx.y * N_TOTAL + n] = bi; }
        else outIdx[n] = bi;
    }
}

__global__ void vq_merge_fb(const float* __restrict__ partS, const int* __restrict__ partI,
                            int* __restrict__ out) {
    int n = blockIdx.x * 256 + threadIdx.x;
    float s0 = partS[n], s1 = partS[N_TOTAL + n];
    int   i0 = partI[n], i1 = partI[N_TOTAL + n];
    out[n] = (s1 < s0) ? i1 : i0;
}

extern "C" void kernel_launch(void* const* d_in, const int* in_sizes, int n_in,
                              void* d_out, int out_size, void* d_ws, size_t ws_size,
                              hipStream_t stream) {
    const float4* lat = (const float4*)d_in[0];
    const float4* cb  = (const float4*)d_in[1];
    int* out = (int*)d_out;
    char* ws = (char*)d_ws;

    if (ws_size >= WS_NEED) {
        float* c2   = (float*)(ws + O_C2);
        uint4* cbSw = (uint4*)(ws + O_CBSW);
        float* pS1  = (float*)(ws + O_PS1);
        float* pS2  = (float*)(ws + O_PS2);
        int*   pI1  = (int*)(ws + O_PI1);
        int*   cnt  = (int*)(ws + O_CNT);
        int*   list = (int*)(ws + O_LIST);
        unsigned long long* slot = (unsigned long long*)(ws + O_SLOT);

        vq_prep<<<256, 256, 0, stream>>>(cb, cbSw, c2, cnt);
        vq_mfma<<<dim3(256, NPART), 256, 0, stream>>>(lat, cbSw, c2, pS1, pS2, pI1);
        vq_merge8<<<128, 256, 0, stream>>>(pS1, pS2, pI1, out, cnt, list, slot);
        vq_exact3<<<dim3(64, 8), 256, 0, stream>>>(lat, cb, c2, cnt, list, slot);
        vq_write<<<128, 256, 0, stream>>>(cnt, list, slot, out);
    } else {
        float* c2 = (float*)ws;
        vq_norms_fb<<<128, 256, 0, stream>>>(cb, c2);
        const size_t needSplit = 32768u + 2u * N_TOTAL * 4u + 2u * N_TOTAL * 4u + 64u;
        if (ws_size >= needSplit) {
            float* partS = (float*)(ws + 32768);
            int*   partI = (int*)(ws + 32768 + 2 * N_TOTAL * 4);
            dim3 grid(N_TOTAL / BM, 2);
            vq_fp32<<<grid, 256, 0, stream>>>(lat, cb, c2, (K_CODES / BN) / 2, out, partS, partI, 1);
            vq_merge_fb<<<N_TOTAL / 256, 256, 0, stream>>>(partS, partI, out);
        } else {
            dim3 grid(N_TOTAL / BM, 1);
            vq_fp32<<<grid, 256, 0, stream>>>(lat, cb, c2, K_CODES / BN, out, nullptr, nullptr, 0);
        }
    }
}

// Round 9
// 252.160 us; speedup vs baseline: 2.5100x; 2.5100x over previous
//
#include <hip/hip_runtime.h>
#include <stdint.h>

// VQ-VAE nearest-codebook index: N=32768 queries, D=64, K=8192 codes.
// R9: phase A rebuilt on mfma_f32_16x16x32_bf16 (acc=4 regs) with 2 query-
// tiles/wave -> natural ~105 VGPR (vs ~192 for the 32x32 tile, which only
// fits at 2 waves/SIMD and stalls at 52% issue-busy; capping tighter spills:
// R4/R8 evidence). (256,3) cap=170 >> natural -> no spill, 3-4 waves/SIMD.
// B-fragments in lane-linear LDS layout (ds_read_b128 base+lane*16).
// bf16x3 hi/lo split + s2 certification (R6-proven); flagged queries re-solved
// exactly in fp32 (vq_exact3, k-tiled shared codebook). Split-K=4.

#define N_TOTAL 32768
#define K_CODES 8192
#define EPS_GAP 0.015f
#define NPART   4

typedef __attribute__((ext_vector_type(4))) float  floatx4;
typedef __attribute__((ext_vector_type(8))) __bf16 bf16x8;

// ---- workspace layout (bytes) ----
#define O_C2    0u          // 8192 f32
#define O_CBSW  32768u      // [512 tile16][hi/lo][h][g][code16] = 2 MB
#define O_PS1   2129920u    // 4*32768 f32
#define O_PS2   2654208u    // 4*32768 f32
#define O_PI1   3178496u    // 4*32768 i32
#define O_CNT   3702784u
#define O_LIST  3703040u    // 32768 int
#define O_SLOT  3834112u    // 32768 u64
#define WS_NEED 4096256u

#if defined(__has_builtin)
#if __has_builtin(__builtin_amdgcn_fmed3f)
#define MED3(a, b, c) __builtin_amdgcn_fmed3f((a), (b), (c))
#endif
#endif
#ifndef MED3
#define MED3(a, b, c) fminf((c), fmaxf((a), (b)))
#endif

__device__ __forceinline__ unsigned int fkey(float s) {
    unsigned int u = __float_as_uint(s);
    return (u & 0x80000000u) ? ~u : (u | 0x80000000u);
}

__device__ __forceinline__ void load_lds16(const void* g, void* l) {
    __builtin_amdgcn_global_load_lds(
        (const __attribute__((address_space(1))) unsigned int*)g,
        (__attribute__((address_space(3))) unsigned int*)l, 16, 0, 0);
}

// ---- prep: codebook -> hi/lo bf16 16x16x32-B-fragment layout + norms ----
// work item t = (code, h, g): 8 dims at h*32+g*8. cbSw uint4 index:
// tile*256 + p*128 + h*64 + g*16 + (code&15), p=0 hi / p=1 lo.
__global__ __launch_bounds__(256) void vq_prep16(
    const float4* __restrict__ cb, uint4* __restrict__ cbSw,
    float* __restrict__ c2, int* __restrict__ cnt) {
    const int t = blockIdx.x * 256 + threadIdx.x;   // 65536 items
    if (t == 0) *cnt = 0;
    const int code = t >> 3, sub = t & 7, h = sub >> 2, g = sub & 3;
    float4 f0 = cb[(size_t)code * 16 + h * 8 + g * 2];
    float4 f1 = cb[(size_t)code * 16 + h * 8 + g * 2 + 1];
    float x[8] = {f0.x, f0.y, f0.z, f0.w, f1.x, f1.y, f1.z, f1.w};
    bf16x8 hv, lv;
    float ss = 0.f;
#pragma unroll
    for (int i = 0; i < 8; ++i) {
        float v  = x[i];
        __bf16 hb = (__bf16)v;           // RNE
        hv[i] = hb;
        lv[i] = (__bf16)(v - (float)hb);
        ss += v * v;
    }
    const int base = (code >> 4) * 256 + h * 64 + g * 16 + (code & 15);
    cbSw[base]       = __builtin_bit_cast(uint4, hv);
    cbSw[base + 128] = __builtin_bit_cast(uint4, lv);
    ss += __shfl_xor(ss, 1);
    ss += __shfl_xor(ss, 2);
    ss += __shfl_xor(ss, 4);
    if (sub == 0) c2[code] = ss;
}

// ---- phase A: 128 queries x 2048 codes per block (split-K=4) ----
__global__ __launch_bounds__(256, 3) void vq_mfma16(
    const float4* __restrict__ lat, const uint4* __restrict__ cbSw,
    const float* __restrict__ c2,
    float* __restrict__ pS1, float* __restrict__ pS2, int* __restrict__ pI1) {
    __shared__ uint4 Bs[2048];   // 32 KB: 8 tiles x 256 uint4
    const int tid = threadIdx.x;
    const int wr = tid >> 6, lane = tid & 63;
    const int lm = lane & 15, lg = lane >> 4;
    const int qBaseW = blockIdx.x * 128 + wr * 32;

    // A fragments, split in-kernel: A[m=lane&15][k=(lane>>4)*8+j], halves h=0/1.
    bf16x8 aH[2][2], aL[2][2];
#pragma unroll
    for (int qt = 0; qt < 2; ++qt) {
        const int q = qBaseW + qt * 16 + lm;
#pragma unroll
        for (int h = 0; h < 2; ++h) {
            float4 v0 = lat[(size_t)q * 16 + h * 8 + lg * 2];
            float4 v1 = lat[(size_t)q * 16 + h * 8 + lg * 2 + 1];
            float x[8] = {v0.x, v0.y, v0.z, v0.w, v1.x, v1.y, v1.z, v1.w};
#pragma unroll
            for (int j = 0; j < 8; ++j) {
                float v  = x[j];
                __bf16 hb = (__bf16)v;
                aH[qt][h][j] = hb;
                aL[qt][h][j] = (__bf16)(v - (float)hb);
            }
        }
    }

    float s1[2][4], s2[2][4]; int i1[2][4];
#pragma unroll
    for (int qt = 0; qt < 2; ++qt)
#pragma unroll
        for (int r = 0; r < 4; ++r) { s1[qt][r] = 3e38f; s2[qt][r] = 3e38f; i1[qt][r] = 0; }

    const int kBase = blockIdx.y * 2048;
    const size_t uBase = (size_t)blockIdx.y * 32768;   // uint4 offset of this part

    for (int stage = 0; stage < 16; ++stage) {
        __syncthreads();
#pragma unroll
        for (int i = 0; i < 8; ++i)
            load_lds16(&cbSw[uBase + stage * 2048 + wr * 64 + 256 * i + lane],
                       &Bs[wr * 64 + 256 * i]);
        __syncthreads();

#pragma unroll
        for (int t = 0; t < 8; ++t) {
            const int b = t * 256;
            bf16x8 bH0 = __builtin_bit_cast(bf16x8, Bs[b + lane]);
            bf16x8 bH1 = __builtin_bit_cast(bf16x8, Bs[b + 64 + lane]);
            bf16x8 bL0 = __builtin_bit_cast(bf16x8, Bs[b + 128 + lane]);
            bf16x8 bL1 = __builtin_bit_cast(bf16x8, Bs[b + 192 + lane]);
            const int col = kBase + stage * 128 + t * 16 + lm;
            const float cc = c2[col];
#pragma unroll
            for (int qt = 0; qt < 2; ++qt) {
                floatx4 acc = {0.f, 0.f, 0.f, 0.f};
                acc = __builtin_amdgcn_mfma_f32_16x16x32_bf16(aH[qt][0], bH0, acc, 0, 0, 0);
                acc = __builtin_amdgcn_mfma_f32_16x16x32_bf16(aH[qt][1], bH1, acc, 0, 0, 0);
                acc = __builtin_amdgcn_mfma_f32_16x16x32_bf16(aL[qt][0], bH0, acc, 0, 0, 0);
                acc = __builtin_amdgcn_mfma_f32_16x16x32_bf16(aL[qt][1], bH1, acc, 0, 0, 0);
                acc = __builtin_amdgcn_mfma_f32_16x16x32_bf16(aH[qt][0], bL0, acc, 0, 0, 0);
                acc = __builtin_amdgcn_mfma_f32_16x16x32_bf16(aH[qt][1], bL1, acc, 0, 0, 0);
#pragma unroll
                for (int r = 0; r < 4; ++r) {
                    float s = fmaf(-2.f, acc[r], cc);
                    s2[qt][r] = MED3(s, s1[qt][r], s2[qt][r]);   // min(s2,max(s,s1))
                    bool lt = s < s1[qt][r];
                    i1[qt][r] = lt ? col : i1[qt][r];
                    s1[qt][r] = lt ? s : s1[qt][r];
                }
            }
        }
    }

    // reduce (s1,i1,s2) across the 16 column-lanes of each row group
#pragma unroll
    for (int mask = 1; mask <= 8; mask <<= 1) {
#pragma unroll
        for (int qt = 0; qt < 2; ++qt)
#pragma unroll
            for (int r = 0; r < 4; ++r) {
                float o1 = __shfl_xor(s1[qt][r], mask);
                float o2 = __shfl_xor(s2[qt][r], mask);
                int   oi = __shfl_xor(i1[qt][r], mask);
                float n2 = fminf(fminf(s2[qt][r], o2), fmaxf(s1[qt][r], o1));
                bool take = (o1 < s1[qt][r]) || (o1 == s1[qt][r] && oi < i1[qt][r]);
                s1[qt][r] = take ? o1 : s1[qt][r];
                i1[qt][r] = take ? oi : i1[qt][r];
                s2[qt][r] = n2;
            }
    }

    if (lm == 0) {
        const int o0 = blockIdx.y * N_TOTAL;
#pragma unroll
        for (int qt = 0; qt < 2; ++qt)
#pragma unroll
            for (int r = 0; r < 4; ++r) {
                // C/D layout: row = (lane>>4)*4 + r, col = lane&15
                int q = qBaseW + qt * 16 + lg * 4 + r;
                pS1[o0 + q] = s1[qt][r];
                pS2[o0 + q] = s2[qt][r];
                pI1[o0 + q] = i1[qt][r];
            }
    }
}

// ---- merge 4 split-K partitions, write indices, flag near-ties ----
__global__ void vq_merge4(const float* __restrict__ pS1, const float* __restrict__ pS2,
                          const int* __restrict__ pI1, int* __restrict__ out,
                          int* __restrict__ cnt, int* __restrict__ list,
                          unsigned long long* __restrict__ slot) {
    int q = blockIdx.x * 256 + threadIdx.x;
    float g1 = 3e38f, g2 = 3e38f;
    int   gi = 0x7FFFFFFF;
#pragma unroll
    for (int p = 0; p < NPART; ++p) {
        float s1p = pS1[p * N_TOTAL + q];
        float s2p = pS2[p * N_TOTAL + q];
        int   i1p = pI1[p * N_TOTAL + q];
        bool take = (s1p < g1) || (s1p == g1 && i1p < gi);
        g2 = fminf(g2, fminf(s2p, take ? g1 : s1p));
        if (take) { g1 = s1p; gi = i1p; }
    }
    out[q] = gi;
    if (g2 - g1 < EPS_GAP) {
        int e = atomicAdd(cnt, 1);
        list[e] = q;
        slot[e] = 0xFFFFFFFFFFFFFFFFull;
    }
}

// ---- phase B: exact fp32, k-tiled shared-codebook scan ----
#define CBP 129
__global__ __launch_bounds__(256) void vq_exact3(
    const float4* __restrict__ lat, const float4* __restrict__ cb,
    const float* __restrict__ c2, const int* __restrict__ cnt,
    const int* __restrict__ list, unsigned long long* __restrict__ slot) {
    __shared__ float CbT[64 * CBP];
    __shared__ float c2s[128];
    const int n = *cnt;
    if (n == 0) return;
    const int ks = blockIdx.x;
    const int egrp = blockIdx.y;
    const int tid = threadIdx.x;
    for (int i = tid; i < 2048; i += 256) {
        int code = i >> 4, d4 = i & 15;
        float4 v = cb[(size_t)(ks * 128 + code) * 16 + d4];
        CbT[(d4 * 4 + 0) * CBP + code] = v.x;
        CbT[(d4 * 4 + 1) * CBP + code] = v.y;
        CbT[(d4 * 4 + 2) * CBP + code] = v.z;
        CbT[(d4 * 4 + 3) * CBP + code] = v.w;
    }
    if (tid < 128) c2s[tid] = c2[ks * 128 + tid];
    __syncthreads();

    const int code = tid >> 1, dh = tid & 1;
    for (int e = egrp; e < n; e += 8) {
        const int qq = list[e];
        const float4* qp = lat + (size_t)qq * 16 + dh * 8;
        float dot = 0.f;
#pragma unroll
        for (int j = 0; j < 8; ++j) {
            float4 qv = qp[j];
            dot += qv.x * CbT[(dh * 32 + j * 4 + 0) * CBP + code]
                 + qv.y * CbT[(dh * 32 + j * 4 + 1) * CBP + code]
                 + qv.z * CbT[(dh * 32 + j * 4 + 2) * CBP + code]
                 + qv.w * CbT[(dh * 32 + j * 4 + 3) * CBP + code];
        }
        dot += __shfl_xor(dot, 1);
        float s = c2s[code] - 2.f * dot;
        unsigned long long p =
            ((unsigned long long)fkey(s) << 32) | (unsigned)(ks * 128 + code);
#pragma unroll
        for (int mask = 1; mask <= 32; mask <<= 1) {
            unsigned long long o = __shfl_xor(p, mask);
            p = o < p ? o : p;
        }
        if ((tid & 63) == 0) atomicMin(&slot[e], p);
    }
}

// ---- write back exact answers for flagged queries ----
__global__ void vq_write(const int* __restrict__ cnt, const int* __restrict__ list,
                         const unsigned long long* __restrict__ slot,
                         int* __restrict__ out) {
    int t = blockIdx.x * 256 + threadIdx.x;
    if (t < *cnt) out[list[t]] = (int)(slot[t] & 0xFFFFFFFFull);
}

// ================= fallback: validated round-1 fp32 path =================
#define BM 128
#define BN 128
#define PAD 68

__global__ void vq_norms_fb(const float4* __restrict__ cb, float* __restrict__ c2) {
    int t = blockIdx.x * 256 + threadIdx.x;
    int r = t >> 2, p = t & 3;
    float s = 0.f;
#pragma unroll
    for (int i = 0; i < 4; ++i) {
        float4 v = cb[r * 16 + p * 4 + i];
        s += v.x * v.x + v.y * v.y + v.z * v.z + v.w * v.w;
    }
    s += __shfl_xor(s, 1);
    s += __shfl_xor(s, 2);
    if (p == 0) c2[r] = s;
}

__global__ __launch_bounds__(256) void vq_fp32(
    const float4* __restrict__ lat, const float4* __restrict__ cb,
    const float* __restrict__ c2, int ktPer,
    int* __restrict__ outIdx, float* __restrict__ partS, int* __restrict__ partI,
    int writePartial) {
    __shared__ float As[BM][PAD];
    __shared__ float Bsf[BN][PAD];
    __shared__ float c2s[BN];
    const int tid = threadIdx.x;
    const int tx = tid & 15;
    const int ty = tid >> 4;
    const int nBase = blockIdx.x * BM;
    const int kt0 = blockIdx.y * ktPer;
    const int ktN = kt0 + ktPer;
#pragma unroll
    for (int r = 0; r < 8; ++r) {
        int f = tid + 256 * r;
        int mm = f >> 4, d4 = f & 15;
        float4 v = lat[(size_t)(nBase + mm) * 16 + d4];
        *(float4*)&As[mm][d4 * 4] = v;
    }
    float best[8]; int bidx[8];
#pragma unroll
    for (int ii = 0; ii < 8; ++ii) { best[ii] = 3e38f; bidx[ii] = 0; }
    for (int kt = kt0; kt < ktN; ++kt) {
        const int kbase = kt * BN;
        __syncthreads();
#pragma unroll
        for (int r = 0; r < 8; ++r) {
            int f = tid + 256 * r;
            int k = f >> 4, d4 = f & 15;
            float4 v = cb[(size_t)(kbase + k) * 16 + d4];
            *(float4*)&Bsf[k][d4 * 4] = v;
        }
        if (tid < BN) c2s[tid] = c2[kbase + tid];
        __syncthreads();
        float acc[8][8];
#pragma unroll
        for (int ii = 0; ii < 8; ++ii)
#pragma unroll
            for (int jj = 0; jj < 8; ++jj) acc[ii][jj] = 0.f;
#pragma unroll 4
        for (int d4 = 0; d4 < 16; ++d4) {
            float4 a[8], b[8];
#pragma unroll
            for (int ii = 0; ii < 8; ++ii) a[ii] = *(const float4*)&As[tx + 16 * ii][d4 * 4];
#pragma unroll
            for (int jj = 0; jj < 8; ++jj) b[jj] = *(const float4*)&Bsf[ty + 16 * jj][d4 * 4];
#pragma unroll
            for (int ii = 0; ii < 8; ++ii)
#pragma unroll
                for (int jj = 0; jj < 8; ++jj)
                    acc[ii][jj] += a[ii].x * b[jj].x + a[ii].y * b[jj].y
                                 + a[ii].z * b[jj].z + a[ii].w * b[jj].w;
        }
#pragma unroll
        for (int jj = 0; jj < 8; ++jj) {
            int k = kbase + ty + 16 * jj;
            float cc = c2s[ty + 16 * jj];
#pragma unroll
            for (int ii = 0; ii < 8; ++ii) {
                float s = cc - 2.f * acc[ii][jj];
                if (s < best[ii]) { best[ii] = s; bidx[ii] = k; }
            }
        }
    }
    __syncthreads();
    float* redS = &As[0][0];
    int*   redI = (int*)&Bsf[0][0];
#pragma unroll
    for (int ii = 0; ii < 8; ++ii) {
        int mm = tx + 16 * ii;
        redS[ty * BM + mm] = best[ii];
        redI[ty * BM + mm] = bidx[ii];
    }
    __syncthreads();
    if (tid < BM) {
        int mm = tid;
        float bs = redS[mm]; int bi = redI[mm];
#pragma unroll
        for (int t = 1; t < 16; ++t) {
            float s = redS[t * BM + mm]; int i = redI[t * BM + mm];
            if (s < bs || (s == bs && i < bi)) { bs = s; bi = i; }
        }
        int n = nBase + mm;
        if (writePartial) { partS[blockIdx.y * N_TOTAL + n] = bs; partI[blockIdx.y * N_TOTAL + n] = bi; }
        else outIdx[n] = bi;
    }
}

__global__ void vq_merge_fb(const float* __restrict__ partS, const int* __restrict__ partI,
                            int* __restrict__ out) {
    int n = blockIdx.x * 256 + threadIdx.x;
    float s0 = partS[n], s1 = partS[N_TOTAL + n];
    int   i0 = partI[n], i1 = partI[N_TOTAL + n];
    out[n] = (s1 < s0) ? i1 : i0;
}

extern "C" void kernel_launch(void* const* d_in, const int* in_sizes, int n_in,
                              void* d_out, int out_size, void* d_ws, size_t ws_size,
                              hipStream_t stream) {
    const float4* lat = (const float4*)d_in[0];
    const float4* cb  = (const float4*)d_in[1];
    int* out = (int*)d_out;
    char* ws = (char*)d_ws;

    if (ws_size >= WS_NEED) {
        float* c2   = (float*)(ws + O_C2);
        uint4* cbSw = (uint4*)(ws + O_CBSW);
        float* pS1  = (float*)(ws + O_PS1);
        float* pS2  = (float*)(ws + O_PS2);
        int*   pI1  = (int*)(ws + O_PI1);
        int*   cnt  = (int*)(ws + O_CNT);
        int*   list = (int*)(ws + O_LIST);
        unsigned long long* slot = (unsigned long long*)(ws + O_SLOT);

        vq_prep16<<<256, 256, 0, stream>>>(cb, cbSw, c2, cnt);
        vq_mfma16<<<dim3(256, NPART), 256, 0, stream>>>(lat, cbSw, c2, pS1, pS2, pI1);
        vq_merge4<<<128, 256, 0, stream>>>(pS1, pS2, pI1, out, cnt, list, slot);
        vq_exact3<<<dim3(64, 8), 256, 0, stream>>>(lat, cb, c2, cnt, list, slot);
        vq_write<<<128, 256, 0, stream>>>(cnt, list, slot, out);
    } else {
        float* c2 = (float*)ws;
        vq_norms_fb<<<128, 256, 0, stream>>>(cb, c2);
        const size_t needSplit = 32768u + 2u * N_TOTAL * 4u + 2u * N_TOTAL * 4u + 64u;
        if (ws_size >= needSplit) {
            float* partS = (float*)(ws + 32768);
            int*   partI = (int*)(ws + 32768 + 2 * N_TOTAL * 4);
            dim3 grid(N_TOTAL / BM, 2);
            vq_fp32<<<grid, 256, 0, stream>>>(lat, cb, c2, (K_CODES / BN) / 2, out, partS, partI, 1);
            vq_merge_fb<<<N_TOTAL / 256, 256, 0, stream>>>(partS, partI, out);
        } else {
            dim3 grid(N_TOTAL / BM, 1);
            vq_fp32<<<grid, 256, 0, stream>>>(lat, cb, c2, K_CODES / BN, out, nullptr, nullptr, 0);
        }
    }
}